// Round 1
// baseline (376.889 us; speedup 1.0000x reference)
//
#include <hip/hip_runtime.h>
#include <stdint.h>

using s16x8 = __attribute__((ext_vector_type(8))) short;
using f32x4 = __attribute__((ext_vector_type(4))) float;

#define HW 1024
#define INC 256
#define EMB 512

#define OFF_CS 0
#define OFF_CN 8388608
#define OFF_D  16777216
#define OFF_DN 25165824
#define OFF_PO 50331648

__device__ __forceinline__ uint32_t f2bf(float f) {
  uint32_t u = __float_as_uint(f);
  return (u + 0x7FFFu + ((u >> 16) & 1u)) >> 16;
}
// XOR swizzle: spreads 16 fragment-rows over 4 bank groups (reads 4-way instead of 16-way)
__device__ __forceinline__ int lswz(int row, int byte) {
  return byte ^ (((row >> 2) & 7) << 4);
}
__device__ __forceinline__ void gload16(const void* g, void* l) {
  __builtin_amdgcn_global_load_lds((const __attribute__((address_space(1))) uint32_t*)g,
                                   (__attribute__((address_space(3))) uint32_t*)l, 16, 0, 0);
}

// ---------------- K0: normalized rep matrix R[1024][512] bf16, zero norms/psum ----
__global__ __launch_bounds__(64) void k_prep(
    const float* __restrict__ rep_w, const float* __restrict__ rep_b,
    const float* __restrict__ neg_w, const float* __restrict__ neg_b,
    uint16_t* __restrict__ R, float* __restrict__ norms, float* __restrict__ psum) {
  int rb = blockIdx.x, lane = threadIdx.x;       // rb = class*4 + mode
  if (lane < 32) { norms[rb * 32 + lane] = 0.f; psum[rb * 32 + lane] = 0.f; }
  int c = rb >> 2, md = rb & 3;
  const float* w  = (md == 0) ? rep_w : neg_w;
  const float* bb = (md == 0) ? rep_b : neg_b;
  int base = (md == 0) ? c * EMB : (c * 3 + md - 1) * EMB;
  float v[8]; float ss = 0.f;
#pragma unroll
  for (int j = 0; j < 8; ++j) {
    float t = w[base + lane * 8 + j] + bb[base + lane * 8 + j];
    v[j] = t; ss += t * t;
  }
#pragma unroll
  for (int o = 1; o < 64; o <<= 1) ss += __shfl_xor(ss, o, 64);
  float inv = 1.f / fmaxf(sqrtf(ss), 1e-12f);
  uint16_t* dst = R + rb * EMB + lane * 8;
#pragma unroll
  for (int j = 0; j < 8; ++j) dst[j] = (uint16_t)f2bf(v[j] * inv);
}

// ---------------- K1: emb = x * W_emb^T  (M=px, N=e, K=c), write bf16 + norm sumsq --
__global__ __launch_bounds__(256) void k_gemm1(
    const float* __restrict__ x, const float* __restrict__ wemb,
    uint16_t* __restrict__ emb, float* __restrict__ norms) {
  int bid = blockIdx.x;
  int w = (bid & 7) * 128 + (bid >> 3);          // XCD swizzle (1024 = 8*128)
  int e_tile = w & 3, px_tile = w >> 2;
  int e0 = e_tile * 128, px0 = px_tile * 128;
  int bimg = px0 >> 10, hw0 = px0 & 1023;
  int tid = threadIdx.x, lane = tid & 63, wid = tid >> 6;
  int wm = wid >> 1, wn = wid & 1, lr = lane & 15, lk = lane >> 4;
  __shared__ __align__(16) char smA[16384];      // [128 px][64 c] bf16, swizzled
  __shared__ __align__(16) char smB[16384];      // [128 e ][64 c] bf16, swizzled
  f32x4 acc[4][4] = {};
  const float4* x4 = (const float4*)x;
  const float4* w4 = (const float4*)wemb;
  for (int kt = 0; kt < INC; kt += 64) {
    if (kt) __syncthreads();
    // stage A: x rows (c) -> LDS [px][c] bf16 (transpose + convert in regs)
#pragma unroll
    for (int i = 0; i < 4; ++i) {
      int p = tid + i * 256;
      int c2 = p >> 5, px4 = p & 31;             // c-pair index, px float4-chunk
      int gi = ((bimg * INC + kt + c2 * 2) * HW + hw0) >> 2;
      float4 fa = x4[gi + px4];
      float4 fb = x4[gi + 256 + px4];
      float fa_[4] = {fa.x, fa.y, fa.z, fa.w};
      float fb_[4] = {fb.x, fb.y, fb.z, fb.w};
#pragma unroll
      for (int j = 0; j < 4; ++j) {
        int px = px4 * 4 + j;
        uint32_t val = f2bf(fa_[j]) | (f2bf(fb_[j]) << 16);
        *(uint32_t*)(smA + px * 128 + lswz(px, c2 * 4)) = val;
      }
    }
    // stage B: W_emb [e][c] -> LDS bf16 (layout-preserving)
#pragma unroll
    for (int i = 0; i < 8; ++i) {
      int q = tid + i * 256;
      int er = q >> 4, c4 = q & 15;
      float4 f = w4[(((e0 + er) * INC + kt) >> 2) + c4];
      uint2 val;
      val.x = f2bf(f.x) | (f2bf(f.y) << 16);
      val.y = f2bf(f.z) | (f2bf(f.w) << 16);
      *(uint2*)(smB + er * 128 + lswz(er, c4 * 8)) = val;
    }
    __syncthreads();
#pragma unroll
    for (int kk = 0; kk < 64; kk += 32) {
      s16x8 a[4], b[4];
#pragma unroll
      for (int mi = 0; mi < 4; ++mi) {
        int row = wm * 64 + mi * 16 + lr;
        a[mi] = *(const s16x8*)(smA + row * 128 + lswz(row, (kk + lk * 8) * 2));
      }
#pragma unroll
      for (int ni = 0; ni < 4; ++ni) {
        int row = wn * 64 + ni * 16 + lr;
        b[ni] = *(const s16x8*)(smB + row * 128 + lswz(row, (kk + lk * 8) * 2));
      }
#pragma unroll
      for (int mi = 0; mi < 4; ++mi)
#pragma unroll
        for (int ni = 0; ni < 4; ++ni)
          acc[mi][ni] = __builtin_amdgcn_mfma_f32_16x16x32_bf16(a[mi], b[ni], acc[mi][ni], 0, 0, 0);
    }
  }
  // epilogue: emb bf16 (lane-pair packed u32 stores) + per-pixel sumsq atomics
#pragma unroll
  for (int mi = 0; mi < 4; ++mi) {
#pragma unroll
    for (int r = 0; r < 4; ++r) {
      int pxg = px0 + wm * 64 + mi * 16 + lk * 4 + r;
      float ss = 0.f;
#pragma unroll
      for (int ni = 0; ni < 4; ++ni) {
        float v = acc[mi][ni][r];
        ss += v * v;
        uint32_t bf = f2bf(v);
        uint32_t other = (uint32_t)__shfl_xor((int)bf, 1, 64);
        if (!(lane & 1)) {
          int e = e0 + wn * 64 + ni * 16 + lr;
          *(uint32_t*)(emb + pxg * EMB + e) = bf | (other << 16);
        }
      }
#pragma unroll
      for (int o = 1; o < 16; o <<= 1) ss += __shfl_xor(ss, o, 64);
      if (lr == 0) atomicAdd(&norms[pxg], ss);
    }
  }
}

// ---------------- K2: dots = R * emb^T (M=reps, N=px) + full fused epilogue --------
__global__ __launch_bounds__(256) void k_gemm2(
    const uint16_t* __restrict__ Rm, const uint16_t* __restrict__ emb,
    const float* __restrict__ norms, float* __restrict__ out, float* __restrict__ psum) {
  int bid = blockIdx.x;
  int w = (bid & 7) * 256 + (bid >> 3);          // XCD swizzle (2048 = 8*256)
  int px_tile = w >> 3, rep_tile = w & 7;
  int px0 = px_tile * 128, r0 = rep_tile * 128;
  int bimg = px0 >> 10;
  int tid = threadIdx.x, lane = tid & 63, wid = tid >> 6;
  int wm = wid >> 1, wn = wid & 1, lr = lane & 15, lk = lane >> 4;
  __shared__ __align__(16) char smA[16384];      // R tile  [128 rep][64 k]
  __shared__ __align__(16) char smB[16384];      // emb tile[128 px ][64 k]
  f32x4 acc[4][4] = {};
  const char* Rb = (const char*)Rm;
  const char* Eb = (const char*)emb;
  int rowq = lane >> 3;                          // row within 1KB chunk
  int byteq = (lane & 7) * 16;
  for (int kt = 0; kt < EMB; kt += 64) {
    if (kt) __syncthreads();
#pragma unroll
    for (int i = 0; i < 4; ++i) {
      int chunk = wid + i * 4;                   // wave-uniform
      int row = chunk * 8 + rowq;
      int sb = byteq ^ (((row >> 2) & 7) << 4);  // pre-swizzled global source (m173)
      gload16(Rb + (r0 + row) * 1024 + kt * 2 + sb, smA + chunk * 1024);
      gload16(Eb + (px0 + row) * 1024 + kt * 2 + sb, smB + chunk * 1024);
    }
    __syncthreads();
#pragma unroll
    for (int kk = 0; kk < 64; kk += 32) {
      s16x8 a[4], b[4];
#pragma unroll
      for (int mi = 0; mi < 4; ++mi) {
        int row = wm * 64 + mi * 16 + lr;
        a[mi] = *(const s16x8*)(smA + row * 128 + lswz(row, (kk + lk * 8) * 2));
      }
#pragma unroll
      for (int ni = 0; ni < 4; ++ni) {
        int row = wn * 64 + ni * 16 + lr;
        b[ni] = *(const s16x8*)(smB + row * 128 + lswz(row, (kk + lk * 8) * 2));
      }
#pragma unroll
      for (int mi = 0; mi < 4; ++mi)
#pragma unroll
        for (int ni = 0; ni < 4; ++ni)
          acc[mi][ni] = __builtin_amdgcn_mfma_f32_16x16x32_bf16(a[mi], b[ni], acc[mi][ni], 0, 0, 0);
    }
  }
  float invn[4], psacc[4];
#pragma unroll
  for (int ni = 0; ni < 4; ++ni) {
    int px = px0 + wn * 64 + ni * 16 + lr;
    invn[ni] = rsqrtf(fmaxf(norms[px], 1e-24f));
    psacc[ni] = 0.f;
  }
#pragma unroll
  for (int mi = 0; mi < 4; ++mi) {
    int repb = r0 + wm * 64 + mi * 16 + lk * 4;  // reg r => rep repb+r = class*4+mode
    int cls = repb >> 2;
#pragma unroll
    for (int ni = 0; ni < 4; ++ni) {
      int px = px0 + wn * 64 + ni * 16 + lr;
      int hw = px & 1023;
      float in = invn[ni];
      float d0 = acc[mi][ni][0] * in;
      float d1 = acc[mi][ni][1] * in;
      float d2 = acc[mi][ni][2] * in;
      float d3 = acc[mi][ni][3] * in;
      float q0 = fmaxf(2.f - 2.f * d0, 0.f);     // dist^2, pos
      float q1 = fmaxf(2.f - 2.f * d1, 0.f);
      float q2 = fmaxf(2.f - 2.f * d2, 0.f);
      float q3 = fmaxf(2.f - 2.f * d3, 0.f);
      float dist0 = sqrtf(q0);
      float qmin = fminf(q1, fminf(q2, q3));
      float negmin = sqrtf(qmin);
      float p_ori = __expf(-2.f * q0);           // inv2s2 = 2
      float cneg  = __expf(-2.f * qmin);
      float pen = 0.3f * fmaxf(2.f - negmin, 0.f);
      float tt = dist0 + pen;
      float probs = __expf(-2.f * tt * tt);
      int bo = (bimg * 256 + cls) * HW + hw;
      out[OFF_D + bo]  = dist0;
      out[OFF_PO + bo] = p_ori;
      out[OFF_CN + bo] = cneg;
      out[OFF_CS + bo] = probs;                  // unnormalized; K3 divides
      int bn = (bimg * 768 + cls * 3) * HW + hw;
      out[OFF_DN + bn]          = sqrtf(q1);
      out[OFF_DN + bn + HW]     = sqrtf(q2);
      out[OFF_DN + bn + 2 * HW] = sqrtf(q3);
      psacc[ni] += probs;
    }
  }
#pragma unroll
  for (int ni = 0; ni < 4; ++ni) {
    float s = psacc[ni];
    s += __shfl_xor(s, 16, 64);
    s += __shfl_xor(s, 32, 64);
    if (lk == 0) atomicAdd(&psum[px0 + wn * 64 + ni * 16 + lr], s);
  }
}

// ---------------- K3: cls_score /= per-pixel class sum --------------------------
__global__ __launch_bounds__(256) void k_norm(float* __restrict__ out,
                                              const float* __restrict__ psum) {
  int idx4 = blockIdx.x * 256 + threadIdx.x;     // one float4 each, 8192 blocks
  int base = idx4 << 2;
  int b = base >> 18, hw = base & 1023;
  float4 p = *(const float4*)&psum[(b << 10) | hw];
  float4* o4 = (float4*)out;
  float4 v = o4[idx4];
  v.x /= p.x; v.y /= p.y; v.z /= p.z; v.w /= p.w;
  o4[idx4] = v;
}

extern "C" void kernel_launch(void* const* d_in, const int* in_sizes, int n_in,
                              void* d_out, int out_size, void* d_ws, size_t ws_size,
                              hipStream_t stream) {
  (void)in_sizes; (void)n_in; (void)out_size; (void)ws_size;
  const float* x     = (const float*)d_in[0];
  const float* wemb  = (const float*)d_in[1];
  const float* rep_w = (const float*)d_in[2];
  const float* rep_b = (const float*)d_in[3];
  const float* neg_w = (const float*)d_in[4];
  const float* neg_b = (const float*)d_in[5];
  float* out = (float*)d_out;
  char* ws = (char*)d_ws;
  uint16_t* R     = (uint16_t*)ws;                              // 1 MB
  float*    norms = (float*)(ws + (1 << 20));                   // 128 KB
  float*    psum  = (float*)(ws + (1 << 20) + (1 << 17));       // 128 KB
  uint16_t* emb   = (uint16_t*)(ws + (1 << 20) + (2 << 17));    // 33.5 MB
  hipLaunchKernelGGL(k_prep,  dim3(1024), dim3(64),  0, stream,
                     rep_w, rep_b, neg_w, neg_b, R, norms, psum);
  hipLaunchKernelGGL(k_gemm1, dim3(1024), dim3(256), 0, stream, x, wemb, emb, norms);
  hipLaunchKernelGGL(k_gemm2, dim3(2048), dim3(256), 0, stream, R, emb, norms, out, psum);
  hipLaunchKernelGGL(k_norm,  dim3(8192), dim3(256), 0, stream, out, psum);
}

// Round 5
// 376.402 us; speedup vs baseline: 1.0013x; 1.0013x over previous
//
#include <hip/hip_runtime.h>
#include <stdint.h>

using s16x8 = __attribute__((ext_vector_type(8))) short;
using f32x4 = __attribute__((ext_vector_type(4))) float;

#define HW 1024
#define INC 256
#define EMB 512
#define NPX 32768

#define OFF_CS 0
#define OFF_CN 8388608
#define OFF_D  16777216
#define OFF_DN 25165824
#define OFF_PO 50331648

__device__ __forceinline__ uint32_t f2bf(float f) {
  uint32_t u = __float_as_uint(f);
  return (u + 0x7FFFu + ((u >> 16) & 1u)) >> 16;
}
// XOR swizzle: spreads 16 fragment-rows over 4 bank groups (reads 4-way instead of 16-way)
__device__ __forceinline__ int lswz(int row, int byte) {
  return byte ^ (((row >> 2) & 7) << 4);
}
__device__ __forceinline__ void gload16(const void* g, void* l) {
  __builtin_amdgcn_global_load_lds((const __attribute__((address_space(1))) uint32_t*)g,
                                   (__attribute__((address_space(3))) uint32_t*)l, 16, 0, 0);
}

// ---------------- K0: normalized rep matrix R[1024][512] bf16 ---------------------
__global__ __launch_bounds__(64) void k_prep(
    const float* __restrict__ rep_w, const float* __restrict__ rep_b,
    const float* __restrict__ neg_w, const float* __restrict__ neg_b,
    uint16_t* __restrict__ R) {
  int rb = blockIdx.x, lane = threadIdx.x;       // rb = class*4 + mode
  int c = rb >> 2, md = rb & 3;
  const float* w  = (md == 0) ? rep_w : neg_w;
  const float* bb = (md == 0) ? rep_b : neg_b;
  int base = (md == 0) ? c * EMB : (c * 3 + md - 1) * EMB;
  float v[8]; float ss = 0.f;
#pragma unroll
  for (int j = 0; j < 8; ++j) {
    float t = w[base + lane * 8 + j] + bb[base + lane * 8 + j];
    v[j] = t; ss += t * t;
  }
#pragma unroll
  for (int o = 1; o < 64; o <<= 1) ss += __shfl_xor(ss, o, 64);
  float inv = 1.f / fmaxf(sqrtf(ss), 1e-12f);
  uint16_t* dst = R + rb * EMB + lane * 8;
#pragma unroll
  for (int j = 0; j < 8; ++j) dst[j] = (uint16_t)f2bf(v[j] * inv);
}

// ---------------- K1: emb = x * W_emb^T  (M=px, N=e, K=c), bf16 out + norm partials
__global__ __launch_bounds__(256) void k_gemm1(
    const float* __restrict__ x, const float* __restrict__ wemb,
    uint16_t* __restrict__ emb, float* __restrict__ nparts) {
  int bid = blockIdx.x;
  int w = (bid & 7) * 128 + (bid >> 3);          // XCD swizzle (1024 = 8*128)
  int e_tile = w & 3, px_tile = w >> 2;
  int e0 = e_tile * 128, px0 = px_tile * 128;
  int bimg = px0 >> 10, hw0 = px0 & 1023;
  int tid = threadIdx.x, lane = tid & 63, wid = tid >> 6;
  int wm = wid >> 1, wn = wid & 1, lr = lane & 15, lk = lane >> 4;
  __shared__ __align__(16) char smA[16384];      // [128 px][64 c] bf16, swizzled
  __shared__ __align__(16) char smB[16384];      // [128 e ][64 c] bf16, swizzled
  f32x4 acc[4][4] = {};
  const float4* x4 = (const float4*)x;
  const float4* w4 = (const float4*)wemb;
  for (int kt = 0; kt < INC; kt += 64) {
    if (kt) __syncthreads();
    // stage A: x rows (c) -> LDS [px][c] bf16 (transpose + convert in regs)
#pragma unroll
    for (int i = 0; i < 4; ++i) {
      int p = tid + i * 256;
      int c2 = p >> 5, px4 = p & 31;             // c-pair index, px float4-chunk
      int gi = ((bimg * INC + kt + c2 * 2) * HW + hw0) >> 2;
      float4 fa = x4[gi + px4];
      float4 fb = x4[gi + 256 + px4];
      float fa_[4] = {fa.x, fa.y, fa.z, fa.w};
      float fb_[4] = {fb.x, fb.y, fb.z, fb.w};
#pragma unroll
      for (int j = 0; j < 4; ++j) {
        int px = px4 * 4 + j;
        uint32_t val = f2bf(fa_[j]) | (f2bf(fb_[j]) << 16);
        *(uint32_t*)(smA + px * 128 + lswz(px, c2 * 4)) = val;
      }
    }
    // stage B: W_emb [e][c] -> LDS bf16 (layout-preserving)
#pragma unroll
    for (int i = 0; i < 8; ++i) {
      int q = tid + i * 256;
      int er = q >> 4, c4 = q & 15;
      float4 f = w4[(((e0 + er) * INC + kt) >> 2) + c4];
      uint2 val;
      val.x = f2bf(f.x) | (f2bf(f.y) << 16);
      val.y = f2bf(f.z) | (f2bf(f.w) << 16);
      *(uint2*)(smB + er * 128 + lswz(er, c4 * 8)) = val;
    }
    __syncthreads();
#pragma unroll
    for (int kk = 0; kk < 64; kk += 32) {
      s16x8 a[4], b[4];
#pragma unroll
      for (int mi = 0; mi < 4; ++mi) {
        int row = wm * 64 + mi * 16 + lr;
        a[mi] = *(const s16x8*)(smA + row * 128 + lswz(row, (kk + lk * 8) * 2));
      }
#pragma unroll
      for (int ni = 0; ni < 4; ++ni) {
        int row = wn * 64 + ni * 16 + lr;
        b[ni] = *(const s16x8*)(smB + row * 128 + lswz(row, (kk + lk * 8) * 2));
      }
#pragma unroll
      for (int mi = 0; mi < 4; ++mi)
#pragma unroll
        for (int ni = 0; ni < 4; ++ni)
          acc[mi][ni] = __builtin_amdgcn_mfma_f32_16x16x32_bf16(a[mi], b[ni], acc[mi][ni], 0, 0, 0);
    }
  }
  // epilogue: emb bf16 (lane-pair packed u32 stores) + norm partials (NO atomics)
#pragma unroll
  for (int mi = 0; mi < 4; ++mi) {
#pragma unroll
    for (int r = 0; r < 4; ++r) {
      int pxg = px0 + wm * 64 + mi * 16 + lk * 4 + r;
      float ss = 0.f;
#pragma unroll
      for (int ni = 0; ni < 4; ++ni) {
        float v = acc[mi][ni][r];
        ss += v * v;
        uint32_t bf = f2bf(v);
        uint32_t other = (uint32_t)__shfl_xor((int)bf, 1, 64);
        if (!(lane & 1)) {
          int e = e0 + wn * 64 + ni * 16 + lr;
          *(uint32_t*)(emb + pxg * EMB + e) = bf | (other << 16);
        }
      }
      ss += __shfl_xor(ss, 1, 64);
      ss += __shfl_xor(ss, 2, 64);
      ss += __shfl_xor(ss, 4, 64);
      ss += __shfl_xor(ss, 8, 64);
      if (lr == 0) nparts[(e_tile * 2 + wn) * NPX + pxg] = ss;
    }
  }
}

// ---------------- K2: dots = R * emb^T (M=reps, N=px) + fused epilogue, coalesced --
__global__ __launch_bounds__(256) void k_gemm2(
    const uint16_t* __restrict__ Rm, const uint16_t* __restrict__ emb,
    const float* __restrict__ nparts, float* __restrict__ out,
    float* __restrict__ psum_part) {
  int bid = blockIdx.x;
  int w = (bid & 7) * 256 + (bid >> 3);          // XCD swizzle (2048 = 8*256)
  int px_tile = w >> 3, rep_tile = w & 7;
  int px0 = px_tile * 128, r0 = rep_tile * 128;
  int bimg = px0 >> 10;
  int tid = threadIdx.x, lane = tid & 63, wid = tid >> 6;
  int wm = wid >> 1, wn = wid & 1, lr = lane & 15, lk = lane >> 4;
  __shared__ __align__(16) char smA[16384];      // R tile  [128 rep][64 k]
  __shared__ __align__(16) char smB[16384];      // emb tile[128 px ][64 k]
  f32x4 acc[4][4] = {};
  const char* Rb = (const char*)Rm;
  const char* Eb = (const char*)emb;
  int rowq = lane >> 3;                          // row within 1KB chunk
  int byteq = (lane & 7) * 16;
  for (int kt = 0; kt < EMB; kt += 64) {
    if (kt) __syncthreads();
#pragma unroll
    for (int i = 0; i < 4; ++i) {
      int chunk = wid + i * 4;                   // wave-uniform
      int row = chunk * 8 + rowq;
      int sb = byteq ^ (((row >> 2) & 7) << 4);  // pre-swizzled global source (m173)
      gload16(Rb + (r0 + row) * 1024 + kt * 2 + sb, smA + chunk * 1024);
      gload16(Eb + (px0 + row) * 1024 + kt * 2 + sb, smB + chunk * 1024);
    }
    __syncthreads();
#pragma unroll
    for (int kk = 0; kk < 64; kk += 32) {
      s16x8 a[4], b[4];
#pragma unroll
      for (int mi = 0; mi < 4; ++mi) {
        int row = wm * 64 + mi * 16 + lr;
        a[mi] = *(const s16x8*)(smA + row * 128 + lswz(row, (kk + lk * 8) * 2));
      }
#pragma unroll
      for (int ni = 0; ni < 4; ++ni) {
        int row = wn * 64 + ni * 16 + lr;
        b[ni] = *(const s16x8*)(smB + row * 128 + lswz(row, (kk + lk * 8) * 2));
      }
#pragma unroll
      for (int mi = 0; mi < 4; ++mi)
#pragma unroll
        for (int ni = 0; ni < 4; ++ni)
          acc[mi][ni] = __builtin_amdgcn_mfma_f32_16x16x32_bf16(a[mi], b[ni], acc[mi][ni], 0, 0, 0);
    }
  }
  __syncthreads();                               // LDS loop-use done; reuse as scratch
  // per-wave transpose scratch in smA: 4 rows (lk) x 64 px, row stride 288 B
  char* ep = smA + wid * 1184;
  int hwbase = (px0 & 1023) + wn * 64;
  int obase = (bimg * 256) * HW + hwbase;        // element base for [B,C,H,W] planes
  float invn[4], psacc[4];
#pragma unroll
  for (int ni = 0; ni < 4; ++ni) {
    int px = px0 + wn * 64 + ni * 16 + lr;
    float s = 0.f;
#pragma unroll
    for (int t = 0; t < 8; ++t) s += nparts[t * NPX + px];
    invn[ni] = rsqrtf(fmaxf(s, 1e-24f));
    psacc[ni] = 0.f;
  }
#pragma unroll
  for (int mi = 0; mi < 4; ++mi) {
    int clsl = wm * 16 + mi * 4 + lk;            // class within block [0,32)
    int cls = (r0 >> 2) + clsl;                  // global class
    float pl[7][4];                              // [plane][ni], all indices static
#pragma unroll
    for (int ni = 0; ni < 4; ++ni) {
      float in = invn[ni];
      float d0 = acc[mi][ni][0] * in;
      float d1 = acc[mi][ni][1] * in;
      float d2 = acc[mi][ni][2] * in;
      float d3 = acc[mi][ni][3] * in;
      float q0 = fmaxf(2.f - 2.f * d0, 0.f);     // dist^2
      float q1 = fmaxf(2.f - 2.f * d1, 0.f);
      float q2 = fmaxf(2.f - 2.f * d2, 0.f);
      float q3 = fmaxf(2.f - 2.f * d3, 0.f);
      float dist0 = sqrtf(q0);
      float qmin = fminf(q1, fminf(q2, q3));
      float negmin = sqrtf(qmin);
      float pen = 0.3f * fmaxf(2.f - negmin, 0.f);
      float tt = dist0 + pen;
      float probs = __expf(-2.f * tt * tt);      // inv2s2 = 2
      pl[0][ni] = probs;                         // cls_score (unnormalized)
      pl[1][ni] = __expf(-2.f * qmin);           // cls_score_neg
      pl[2][ni] = dist0;                         // distances
      pl[3][ni] = sqrtf(q1);                     // distances_neg m=0
      pl[4][ni] = sqrtf(q2);                     // m=1
      pl[5][ni] = sqrtf(q3);                     // m=2
      pl[6][ni] = __expf(-2.f * q0);             // probs_ori
      psacc[ni] += probs;
    }
    int bc = obase + cls * HW;
    int bn = OFF_DN + (bimg * 768 + cls * 3) * HW + hwbase;
    int pbase[7] = { OFF_CS + bc, OFF_CN + bc, OFF_D + bc,
                     bn, bn + HW, bn + 2 * HW, OFF_PO + bc };
#pragma unroll
    for (int p = 0; p < 7; ++p) {
#pragma unroll
      for (int ni = 0; ni < 4; ++ni)
        *(float*)(ep + lk * 288 + (ni * 16 + lr) * 4) = pl[p][ni];
      float4 v = *(const float4*)(ep + lk * 288 + lr * 16);   // same-wave, in-order LDS
      *(float4*)(&out[pbase[p] + 4 * lr]) = v;                // 256B-contig segments
    }
  }
#pragma unroll
  for (int ni = 0; ni < 4; ++ni) {
    float s = psacc[ni];
    s += __shfl_xor(s, 16, 64);
    s += __shfl_xor(s, 32, 64);
    if (lk == 0)
      psum_part[(rep_tile * 2 + wm) * NPX + px0 + wn * 64 + ni * 16 + lr] = s;
  }
}

// ---------------- K3: cls_score /= per-pixel class sum (16 partials) --------------
__global__ __launch_bounds__(256) void k_norm(float* __restrict__ out,
                                              const float* __restrict__ psum_part) {
  int idx4 = blockIdx.x * 256 + threadIdx.x;     // one float4 each, 8192 blocks
  int base = idx4 << 2;
  int b = base >> 18, hw = base & 1023;
  int pxb = (b << 10) | hw;
  float sx = 0.f, sy = 0.f, sz = 0.f, sw = 0.f;
#pragma unroll
  for (int t = 0; t < 16; ++t) {
    float4 p = *(const float4*)&psum_part[t * NPX + pxb];
    sx += p.x; sy += p.y; sz += p.z; sw += p.w;
  }
  float4* o4 = (float4*)out;
  float4 v = o4[idx4];
  v.x /= sx; v.y /= sy; v.z /= sz; v.w /= sw;
  o4[idx4] = v;
}

extern "C" void kernel_launch(void* const* d_in, const int* in_sizes, int n_in,
                              void* d_out, int out_size, void* d_ws, size_t ws_size,
                              hipStream_t stream) {
  (void)in_sizes; (void)n_in; (void)out_size; (void)ws_size;
  const float* x     = (const float*)d_in[0];
  const float* wemb  = (const float*)d_in[1];
  const float* rep_w = (const float*)d_in[2];
  const float* rep_b = (const float*)d_in[3];
  const float* neg_w = (const float*)d_in[4];
  const float* neg_b = (const float*)d_in[5];
  float* out = (float*)d_out;
  char* ws = (char*)d_ws;
  uint16_t* R         = (uint16_t*)ws;                      // 1 MB
  float*    nparts    = (float*)(ws + (1 << 20));           // 8  x 32768 x 4 = 1 MB
  float*    psum_part = (float*)(ws + (2 << 20));           // 16 x 32768 x 4 = 2 MB
  uint16_t* emb       = (uint16_t*)(ws + (4 << 20));        // 33.5 MB
  hipLaunchKernelGGL(k_prep,  dim3(1024), dim3(64),  0, stream,
                     rep_w, rep_b, neg_w, neg_b, R);
  hipLaunchKernelGGL(k_gemm1, dim3(1024), dim3(256), 0, stream, x, wemb, emb, nparts);
  hipLaunchKernelGGL(k_gemm2, dim3(2048), dim3(256), 0, stream, R, emb, nparts, out, psum_part);
  hipLaunchKernelGGL(k_norm,  dim3(8192), dim3(256), 0, stream, out, psum_part);
}